// Round 4
// baseline (831.936 us; speedup 1.0000x reference)
//
#include <hip/hip_runtime.h>
#include <stdint.h>

// ---------------------------------------------------------------------------
// Qwen3.5-MoE gated SDPA attention block, MI355X (gfx950)
// Stages: f2b converts -> QKV GEMMs (bf16 MFMA) -> RMSNorm+RoPE pack ->
//         V transpose -> flash attention (fused sigmoid gate) -> out GEMM
// B=2 S=2048 HID=2048 H=16 KV=4 D=128
// ---------------------------------------------------------------------------

using bf16 = unsigned short;                                  // raw bf16 bits
typedef __attribute__((ext_vector_type(8))) short bf16x8;     // MFMA A/B frag
typedef __attribute__((ext_vector_type(4))) float f32x4;      // MFMA C/D frag

__device__ __forceinline__ unsigned short f2bf(float x) {
  unsigned int u = __float_as_uint(x);
  unsigned int r = u + 0x7fffu + ((u >> 16) & 1u);            // RNE
  return (unsigned short)(r >> 16);
}

__device__ __forceinline__ void async_copy16(const void* g, void* l) {
  __builtin_amdgcn_global_load_lds(
      (const __attribute__((address_space(1))) void*)g,
      (__attribute__((address_space(3))) void*)l, 16, 0, 0);
}

// ---------------------------------------------------------------------------
// fp32 -> bf16 convert, 4 elems/thread, exact grid
// ---------------------------------------------------------------------------
__global__ void f2b_kernel(const float* __restrict__ in, bf16* __restrict__ out) {
  int i = (blockIdx.x * 256 + threadIdx.x) * 4;
  float4 v = *(const float4*)(in + i);
  ushort4 o;
  o.x = f2bf(v.x); o.y = f2bf(v.y); o.z = f2bf(v.z); o.w = f2bf(v.w);
  *(ushort4*)(out + i) = o;
}

// ---------------------------------------------------------------------------
// C[m][n] = sum_k A[m][k] * B[n][k]   (A MxK bf16, B NxK bf16, C fp32)
// 128x128 tile, BK=32, 4 waves (2x2), 16 MFMA/wave/K-step (m97 structure)
// T1: XCD-aware block swizzle (grids here are all %8==0 -> bijective)
// ---------------------------------------------------------------------------
__global__ __launch_bounds__(256) void gemm_bt(const bf16* __restrict__ A,
                                               const bf16* __restrict__ B,
                                               float* __restrict__ C,
                                               int M, int N, int K) {
  __shared__ __align__(16) bf16 As[128 * 32];
  __shared__ __align__(16) bf16 Bs[128 * 32];
  const int tid = threadIdx.x;
  const int w = tid >> 6, lane = tid & 63;
  const int wr = w >> 1, wc = w & 1;
  const int li = lane & 15, hi = lane >> 4;

  // XCD swizzle: dispatch-id orig lands on XCD orig%8; give each XCD a
  // contiguous band of tiles (rows) so A-panels stay hot in its L2.
  const int nbx = gridDim.x, nwg = nbx * gridDim.y;
  const int orig = blockIdx.y * nbx + blockIdx.x;
  const int tileid = (orig & 7) * (nwg >> 3) + (orig >> 3);
  const int bm = (tileid / nbx) * 128, bn = (tileid % nbx) * 128;

  f32x4 acc[4][4];
#pragma unroll
  for (int m = 0; m < 4; m++)
#pragma unroll
    for (int n = 0; n < 4; n++) acc[m][n] = (f32x4){0.f, 0.f, 0.f, 0.f};

  const int c0 = tid, c1 = tid + 256;                 // 16B chunk ids (0..511)
  const bf16* Ab = A + (long long)bm * K;
  const bf16* Bb = B + (long long)bn * K;

  for (int k0 = 0; k0 < K; k0 += 32) {
    // stage 128x32 A-tile and B-tile: chunk c -> row c>>2, kcol (c&3)*8
    async_copy16(Ab + (c0 >> 2) * K + k0 + (c0 & 3) * 8, (char*)As + c0 * 16);
    async_copy16(Ab + (c1 >> 2) * K + k0 + (c1 & 3) * 8, (char*)As + c1 * 16);
    async_copy16(Bb + (c0 >> 2) * K + k0 + (c0 & 3) * 8, (char*)Bs + c0 * 16);
    async_copy16(Bb + (c1 >> 2) * K + k0 + (c1 & 3) * 8, (char*)Bs + c1 * 16);
    __syncthreads();   // compiler drains vmcnt before s_barrier -> LDS ready

    bf16x8 af[4], bfv[4];
#pragma unroll
    for (int m = 0; m < 4; m++)
      af[m] = *(const bf16x8*)(As + (wr * 64 + m * 16 + li) * 32 + hi * 8);
#pragma unroll
    for (int n = 0; n < 4; n++)
      bfv[n] = *(const bf16x8*)(Bs + (wc * 64 + n * 16 + li) * 32 + hi * 8);
#pragma unroll
    for (int m = 0; m < 4; m++)
#pragma unroll
      for (int n = 0; n < 4; n++)
        acc[m][n] = __builtin_amdgcn_mfma_f32_16x16x32_bf16(af[m], bfv[n],
                                                            acc[m][n], 0, 0, 0);
    __syncthreads();
  }

  // C/D layout: col = lane&15, row = (lane>>4)*4 + reg
#pragma unroll
  for (int m = 0; m < 4; m++)
#pragma unroll
    for (int n = 0; n < 4; n++) {
      int row = bm + wr * 64 + m * 16 + hi * 4;
      int col = bn + wc * 64 + n * 16 + li;
#pragma unroll
      for (int r = 0; r < 4; r++) C[(long long)(row + r) * N + col] = acc[m][n][r];
    }
}

// ---------------------------------------------------------------------------
// RMSNorm + RoPE + pack to bf16.  One 64-lane wave per (token, head) row;
// lane handles d and d+64 (the rotate_half pair).  q rows also folded by
// 1/sqrt(D).  rows: 0..15 q-heads, 16..19 k-heads.
// ---------------------------------------------------------------------------
__global__ __launch_bounds__(256) void pack_qk(
    const float* __restrict__ qg_raw, const float* __restrict__ kv_raw,
    const float* __restrict__ cosb, const float* __restrict__ sinb,
    const float* __restrict__ qnw, const float* __restrict__ knw,
    bf16* __restrict__ q_pack, bf16* __restrict__ k_pack) {
  int rowid = blockIdx.x * 4 + (threadIdx.x >> 6);
  int lane = threadIdx.x & 63;
  int token = rowid / 20, r = rowid % 20;
  int b = token >> 11, s = token & 2047;
  const float* src; const float* wn; bf16* dst; float scale;
  if (r < 16) {
    src = qg_raw + (long long)token * 4096 + r * 256;  // q part of head r
    wn = qnw;
    dst = q_pack + ((long long)(b * 16 + r) * 2048 + s) * 128;
    scale = 0.08838834764831845f;                      // D^-0.5 folded into q
  } else {
    int kv = r - 16;
    src = kv_raw + (long long)token * 1024 + kv * 128;
    wn = knw;
    dst = k_pack + ((long long)(b * 4 + kv) * 2048 + s) * 128;
    scale = 1.0f;
  }
  float x0 = src[lane], x1 = src[lane + 64];
  float ss = x0 * x0 + x1 * x1;
#pragma unroll
  for (int off = 32; off > 0; off >>= 1) ss += __shfl_xor(ss, off);
  float inv = rsqrtf(ss * (1.0f / 128.0f) + 1e-6f);
  float n0 = x0 * inv * (1.f + wn[lane]);
  float n1 = x1 * inv * (1.f + wn[lane + 64]);
  const float* cp = cosb + (long long)(b * 2048 + s) * 128;
  const float* sp = sinb + (long long)(b * 2048 + s) * 128;
  // rotate_half: out[d] = x[d]*cos[d] - x[d+64]*sin[d];  out[d+64] = x[d+64]*cos[d+64] + x[d]*sin[d+64]
  dst[lane]      = f2bf((n0 * cp[lane]      - n1 * sp[lane])      * scale);
  dst[lane + 64] = f2bf((n1 * cp[lane + 64] + n0 * sp[lane + 64]) * scale);
}

// ---------------------------------------------------------------------------
// V transpose: kv_raw[token][512+c] (fp32) -> vt[b][c][s] (bf16), per batch
// 32x32 LDS tiles, padded.
// ---------------------------------------------------------------------------
__global__ __launch_bounds__(256) void transpose_v(const float* __restrict__ kv_raw,
                                                   bf16* __restrict__ vt) {
  __shared__ float tile[32][33];
  int b = blockIdx.z;
  int c0 = blockIdx.x * 32;     // 0..480
  int s0 = blockIdx.y * 32;     // 0..2016
  int tx = threadIdx.x & 31, ty = threadIdx.x >> 5;
#pragma unroll
  for (int i = 0; i < 32; i += 8)
    tile[ty + i][tx] = kv_raw[(long long)(b * 2048 + s0 + ty + i) * 1024 + 512 + c0 + tx];
  __syncthreads();
#pragma unroll
  for (int i = 0; i < 32; i += 8)
    vt[(long long)(b * 512 + c0 + ty + i) * 2048 + s0 + tx] = f2bf(tile[tx][ty + i]);
}

// ---------------------------------------------------------------------------
// Flash attention, causal, GQA (h -> kv = h/4), fused sigmoid gating.
// 4 waves/block, each wave owns 16 q-rows; 32-key steps; online softmax.
// q_pack already carries the 1/sqrt(D) scale.
// ---------------------------------------------------------------------------
__global__ __launch_bounds__(256) void attn_kernel(
    const bf16* __restrict__ qp, const bf16* __restrict__ kp,
    const bf16* __restrict__ vt, const float* __restrict__ qg_raw,
    bf16* __restrict__ attn_g) {
  __shared__ __align__(16) bf16 Pl[4][16][32];        // per-wave P transpose
  const int w = threadIdx.x >> 6, lane = threadIdx.x & 63;
  const int li = lane & 15, hi = lane >> 4;
  const int bh = blockIdx.y, b = bh >> 4, h = bh & 15, kv = h >> 2;
  const int q0 = blockIdx.x * 64 + w * 16;
  const bf16* qb = qp + ((long long)(b * 16 + h) * 2048 + q0) * 128;
  const bf16* kb = kp + (long long)(b * 4 + kv) * 2048 * 128;
  const bf16* vb = vt + (long long)(b * 4 + kv) * 128 * 2048;

  bf16x8 qf[4];
#pragma unroll
  for (int kd = 0; kd < 4; kd++)
    qf[kd] = *(const bf16x8*)(qb + li * 128 + kd * 32 + hi * 8);

  f32x4 O[8];
#pragma unroll
  for (int t = 0; t < 8; t++) O[t] = (f32x4){0.f, 0.f, 0.f, 0.f};
  float m[4] = {-1e30f, -1e30f, -1e30f, -1e30f};
  float l[4] = {0.f, 0.f, 0.f, 0.f};

  const int ktmax = (q0 + 15) >> 5;
  for (int kt = 0; kt <= ktmax; kt++) {
    const int k0 = kt * 32;
    f32x4 a0 = (f32x4){0.f, 0.f, 0.f, 0.f}, a1 = (f32x4){0.f, 0.f, 0.f, 0.f};
#pragma unroll
    for (int kd = 0; kd < 4; kd++) {
      bf16x8 kf0 = *(const bf16x8*)(kb + (k0 + li) * 128 + kd * 32 + hi * 8);
      bf16x8 kf1 = *(const bf16x8*)(kb + (k0 + 16 + li) * 128 + kd * 32 + hi * 8);
      a0 = __builtin_amdgcn_mfma_f32_16x16x32_bf16(qf[kd], kf0, a0, 0, 0, 0);
      a1 = __builtin_amdgcn_mfma_f32_16x16x32_bf16(qf[kd], kf1, a1, 0, 0, 0);
    }
    if (k0 + 31 > q0) {                               // causal mask (tail tiles)
#pragma unroll
      for (int r = 0; r < 4; r++) {
        int q = q0 + hi * 4 + r;
        if (k0 + li > q)      a0[r] = -1e30f;
        if (k0 + 16 + li > q) a1[r] = -1e30f;
      }
    }
    float alpha[4];
#pragma unroll
    for (int r = 0; r < 4; r++) {
      float vmax = fmaxf(a0[r], a1[r]);
#pragma unroll
      for (int off = 1; off < 16; off <<= 1) vmax = fmaxf(vmax, __shfl_xor(vmax, off));
      float mn = fmaxf(m[r], vmax);
      alpha[r] = __expf(m[r] - mn);
      m[r] = mn;
      float p0 = __expf(a0[r] - mn), p1 = __expf(a1[r] - mn);
      a0[r] = p0; a1[r] = p1;
      float sum = p0 + p1;
#pragma unroll
      for (int off = 1; off < 16; off <<= 1) sum += __shfl_xor(sum, off);
      l[r] = l[r] * alpha[r] + sum;
    }
#pragma unroll
    for (int t = 0; t < 8; t++)
#pragma unroll
      for (int r = 0; r < 4; r++) O[t][r] *= alpha[r];

    // P (C-layout) -> LDS -> A-layout bf16 frag (wave-local round trip)
#pragma unroll
    for (int r = 0; r < 4; r++) {
      Pl[w][hi * 4 + r][li]      = f2bf(a0[r]);
      Pl[w][hi * 4 + r][16 + li] = f2bf(a1[r]);
    }
    asm volatile("s_waitcnt lgkmcnt(0)" ::: "memory"); // drain ds_writes
    __builtin_amdgcn_sched_barrier(0);                 // rule #18: pin ordering
    bf16x8 pa = *(const bf16x8*)(&Pl[w][li][hi * 8]);
#pragma unroll
    for (int t = 0; t < 8; t++) {
      bf16x8 vf = *(const bf16x8*)(vb + (t * 16 + li) * 2048 + k0 + hi * 8);
      O[t] = __builtin_amdgcn_mfma_f32_16x16x32_bf16(pa, vf, O[t], 0, 0, 0);
    }
  }

  // epilogue: /l, sigmoid(gate) fuse, store bf16 [token][H*D]
#pragma unroll
  for (int t = 0; t < 8; t++)
#pragma unroll
    for (int r = 0; r < 4; r++) {
      int s = q0 + hi * 4 + r;
      int col = t * 16 + li;
      float g = qg_raw[(long long)(b * 2048 + s) * 4096 + h * 256 + 128 + col];
      float val = (O[t][r] / l[r]) * (1.f / (1.f + __expf(-g)));
      attn_g[(long long)(b * 2048 + s) * 2048 + h * 128 + col] = f2bf(val);
    }
}

// ---------------------------------------------------------------------------
extern "C" void kernel_launch(void* const* d_in, const int* in_sizes, int n_in,
                              void* d_out, int out_size, void* d_ws, size_t ws_size,
                              hipStream_t stream) {
  const float* hs   = (const float*)d_in[0];
  const float* cosb = (const float*)d_in[1];
  const float* sinb = (const float*)d_in[2];
  const float* Wq   = (const float*)d_in[3];
  const float* Wk   = (const float*)d_in[4];
  const float* Wv   = (const float*)d_in[5];
  const float* Wo   = (const float*)d_in[6];
  const float* qnw  = (const float*)d_in[7];
  const float* knw  = (const float*)d_in[8];
  float* out = (float*)d_out;

  // workspace carve (130,023,424 B), with dead-region aliasing
  const size_t WS_NEEDED = 130023424ull;
  if (ws_size < WS_NEEDED) return;   // diagnostic guard: fail clean, not a GPU fault

  char* p = (char*)d_ws;
  bf16*  hs_bf  = (bf16*)p;  p += 4096ull * 2048 * 2;   // A: dead after GEMMs
  bf16*  wq_bf  = (bf16*)p;  p += 4096ull * 2048 * 2;   // B: dead after qg GEMM
  bf16*  wkv_bf = (bf16*)p;  p += 1024ull * 2048 * 2;   // C
  bf16*  wo_bf  = (bf16*)p;  p += 2048ull * 2048 * 2;   // E
  float* qg_raw = (float*)p; p += 4096ull * 4096 * 4;   // F: gate read by attn
  float* kv_raw = (float*)p; p += 4096ull * 1024 * 4;   // G: dead after pack/transpose
  bf16* q_pack = (bf16*)hs_bf;                          // 16.8MB over A
  bf16* k_pack = (bf16*)wq_bf;                          //  4.2MB over B
  bf16* vt     = (bf16*)((char*)wq_bf + 2ull * 4 * 2048 * 128 * 2); // +4.2MB over B
  bf16* attn_g = (bf16*)kv_raw;                         // 16.8MB over G

  // 1) converts
  f2b_kernel<<<8192, 256, 0, stream>>>(hs, hs_bf);
  f2b_kernel<<<8192, 256, 0, stream>>>(Wq, wq_bf);
  f2b_kernel<<<1024, 256, 0, stream>>>(Wk, wkv_bf);
  f2b_kernel<<<1024, 256, 0, stream>>>(Wv, wkv_bf + 512 * 2048);
  f2b_kernel<<<4096, 256, 0, stream>>>(Wo, wo_bf);

  // 2) projections: qg = hs*Wq^T (4096x4096), kv = hs*[Wk;Wv]^T (4096x1024)
  gemm_bt<<<dim3(32, 32), 256, 0, stream>>>(hs_bf, wq_bf, qg_raw, 4096, 4096, 2048);
  gemm_bt<<<dim3(8, 32), 256, 0, stream>>>(hs_bf, wkv_bf, kv_raw, 4096, 1024, 2048);

  // 3) RMSNorm + RoPE + pack;  4) V transpose
  pack_qk<<<20480, 256, 0, stream>>>(qg_raw, kv_raw, cosb, sinb, qnw, knw, q_pack, k_pack);
  transpose_v<<<dim3(16, 64, 2), 256, 0, stream>>>(kv_raw, vt);

  // 5) flash attention + sigmoid gating
  attn_kernel<<<dim3(32, 32), 256, 0, stream>>>(q_pack, k_pack, vt, qg_raw, attn_g);

  // 6) out = attn_g * Wo^T
  gemm_bt<<<dim3(16, 32), 256, 0, stream>>>(attn_g, wo_bf, out, 4096, 2048, 2048);
}